// Round 10
// baseline (285.582 us; speedup 1.0000x reference)
//
#include <hip/hip_runtime.h>
#include <math.h>

#define N_NODES 100000
#define N_EDGES 1600000
#define EPS_    1e-5f
#define PAD     64          // ELL row capacity; P(Poisson(16) > 64) ~ 1e-20

#define NB_BUILD 6250       // ceil(E/256): one edge per thread, exact
#define NWAVES_L (NB_BUILD * 4)

// ---- bf16 helpers (raw ushort storage, RNE on pack) -----------------------
__device__ __forceinline__ float bf2f(unsigned short u) {
    union { unsigned int i; float f; } v; v.i = (unsigned int)u << 16; return v.f;
}
__device__ __forceinline__ unsigned short f2bf(float f) {
    union { float f; unsigned int i; } v; v.f = f;
    unsigned int b = v.i + 0x7FFFu + ((v.i >> 16) & 1u);   // round-to-nearest-even
    return (unsigned short)(b >> 16);
}

// ---------------------------------------------------------------------------
// Kernel 1: merged ELL build + lin (R8 structure).
// Phase A: one edge/thread: atomicAdd slot + scattered store (TCC-bound).
// Phase B: lin chunk — h=relu(xW1+b1) (recomputed later in gather),
//          hg=hWg stored UNSCALED bf16 (no dependence on final cnt).
// ---------------------------------------------------------------------------
__global__ void build_lin_kernel(const int* __restrict__ src,
                                 const int* __restrict__ dst,
                                 const float* __restrict__ x,
                                 const float* __restrict__ W1,
                                 const float* __restrict__ b1,
                                 const float* __restrict__ Wg,
                                 int* __restrict__ cnt,
                                 int* __restrict__ ell,
                                 unsigned short* __restrict__ hb_g)
{
    __shared__ float sWg[64 * 64];
    const int tl   = threadIdx.x;
    const int gtid = blockIdx.x * 256 + tl;

    // ---- Phase A: edge atomics (issued first; store waits on return) -----
    int pos = -1, d = 0, s = 0;
    if (gtid < N_EDGES) {
        d   = dst[gtid];
        s   = src[gtid];
        pos = atomicAdd(&cnt[d], 1);
    }
    // Stage Wg -> LDS while the atomic is in flight (independent work).
    for (int i = tl; i < 64 * 64; i += 256) sWg[i] = Wg[i];
    if (pos >= 0 && pos < PAD) ell[d * PAD + pos] = s;
    __syncthreads();

    // ---- Phase B: lin chunk (VALU-bound, hides under atomic drain) -------
    const int lane  = tl & 63;
    const int gwave = blockIdx.x * 4 + (tl >> 6);
    for (int n = gwave; n < N_NODES; n += NWAVES_L) {
        const float x0 = x[n * 3 + 0];
        const float x1 = x[n * 3 + 1];
        const float x2 = x[n * 3 + 2];
        float h = x0 * W1[lane] + x1 * W1[64 + lane] + x2 * W1[128 + lane] + b1[lane];
        h = fmaxf(h, 0.0f);

        float acc = 0.0f;
#pragma unroll 16
        for (int k = 0; k < 64; ++k) {
            const float hk = __shfl(h, k, 64);
            acc = fmaf(hk, sWg[k * 64 + lane], acc);
        }
        hb_g[n * 64 + lane] = f2bf(acc);          // unscaled — cnt not final yet
    }
}

// ---------------------------------------------------------------------------
// Kernel 2: per-channel max |hgs| reduction.  lane = channel.
//   maxc[c] = max_n |bf16(hb_g[n][c])| * rsqrt(cnt[n]+1)
// Per-block LDS combine, then one atomicMax per channel per block
// (float>=0 compares correctly as uint).
// ---------------------------------------------------------------------------
__global__ void maxc_kernel(const int* __restrict__ cnt,
                            const unsigned short* __restrict__ hb_g,
                            unsigned int* __restrict__ maxc_bits)
{
    __shared__ float lmax[4][64];
    const int tl   = threadIdx.x;
    const int lane = tl & 63;
    const int w    = tl >> 6;
    const int wave = blockIdx.x * 4 + w;
    const int strd = gridDim.x * 4;

    float m = 0.0f;
    for (int n = wave; n < N_NODES; n += strd) {
        const float di = rsqrtf((float)(cnt[n] + 1));
        const float v  = fabsf(bf2f(hb_g[n * 64 + lane])) * di;
        m = fmaxf(m, v);
    }
    lmax[w][lane] = m;
    __syncthreads();
    if (tl < 64) {
        float mm = fmaxf(fmaxf(lmax[0][tl], lmax[1][tl]),
                         fmaxf(lmax[2][tl], lmax[3][tl]));
        atomicMax(&maxc_bits[tl], __float_as_uint(mm));
    }
}

// ---------------------------------------------------------------------------
// Kernel 3: quantize  hb8[n][c] = int8( hgs[n][c] * 127 / maxc[c] )
// dword-in (2 bf16) / ushort-out (2 int8) grain.
// ---------------------------------------------------------------------------
__global__ void quant_kernel(const int* __restrict__ cnt,
                             const unsigned int* __restrict__ g2,    // hb_g
                             const float* __restrict__ maxc,
                             unsigned short* __restrict__ q16)       // hb8
{
    const int t = blockIdx.x * blockDim.x + threadIdx.x;
    if (t >= N_NODES * 32) return;
    const int node = t >> 5;
    const int c0   = (t & 31) * 2;
    const float di = rsqrtf((float)(cnt[node] + 1));
    const float i0 = 127.0f / fmaxf(maxc[c0],     1e-30f);
    const float i1 = 127.0f / fmaxf(maxc[c0 + 1], 1e-30f);
    const unsigned int v = g2[t];
    const float lo = bf2f((unsigned short)(v & 0xFFFFu)) * di;
    const float hi = bf2f((unsigned short)(v >> 16)) * di;
    int q0 = __float2int_rn(lo * i0);
    int q1 = __float2int_rn(hi * i1);
    q0 = (q0 > 127) ? 127 : ((q0 < -127) ? -127 : q0);
    q1 = (q1 > 127) ? 127 : ((q1 < -127) ? -127 : q1);
    q16[t] = (unsigned short)((q0 & 0xFF) | ((q1 & 0xFF) << 8));
}

// ---------------------------------------------------------------------------
// Kernel 4: gather + epilogue. One wave per dst node, lane = channel.
// int8 rows are 64 B -> exactly ONE cache-line request per edge gather.
// Integer accumulation is EXACT; one decode per node: acc = acc_i*s_c/127.
//   h   = relu(x@W1+b1)   (recomputed: 3 FMAs, weights L1-hot)
//   h2  = relu(dinv[n]*acc + bg);  out = LayerNorm128([h,h2])*gamma + beta
// ---------------------------------------------------------------------------
__global__ void gather_final_kernel(const float* __restrict__ x,
                                    const float* __restrict__ W1,
                                    const float* __restrict__ b1,
                                    const signed char* __restrict__ hb8,
                                    const int* __restrict__ cnt,
                                    const int* __restrict__ ell,
                                    const float* __restrict__ maxc,
                                    const float* __restrict__ bg,
                                    const float* __restrict__ gamma,
                                    const float* __restrict__ beta,
                                    float* __restrict__ out)
{
    const int lane = threadIdx.x & 63;
    const int n    = blockIdx.x * (blockDim.x >> 6) + (threadIdx.x >> 6);
    if (n >= N_NODES) return;

    const int c    = cnt[n];
    const float di = rsqrtf((float)(c + 1));
    const int deg  = (c < PAD) ? c : PAD;
    const int* __restrict__ row = ell + n * PAD;

    // recompute h: per-wave weight loads are L1-hot
    const float w1a = W1[lane], w1b = W1[64 + lane], w1c = W1[128 + lane];
    const float bb  = b1[lane];
    const float x0 = x[n * 3 + 0], x1 = x[n * 3 + 1], x2 = x[n * 3 + 2];
    const float h  = fmaxf(fmaf(x2, w1c, fmaf(x1, w1b, fmaf(x0, w1a, bb))), 0.0f);

    int acc_i = (int)hb8[n * 64 + lane];             // self loop (quantized)

    int j = 0;
    for (; j + 8 <= deg; j += 8) {                   // 8 gathers in flight
        const int4 r0 = *(const int4*)(row + j);
        const int4 r1 = *(const int4*)(row + j + 4);
        const int v0 = (int)hb8[r0.x * 64 + lane];
        const int v1 = (int)hb8[r0.y * 64 + lane];
        const int v2 = (int)hb8[r0.z * 64 + lane];
        const int v3 = (int)hb8[r0.w * 64 + lane];
        const int v4 = (int)hb8[r1.x * 64 + lane];
        const int v5 = (int)hb8[r1.y * 64 + lane];
        const int v6 = (int)hb8[r1.z * 64 + lane];
        const int v7 = (int)hb8[r1.w * 64 + lane];
        acc_i += ((v0 + v1) + (v2 + v3)) + ((v4 + v5) + (v6 + v7));
    }
    if (j + 4 <= deg) {
        const int4 r0 = *(const int4*)(row + j);
        acc_i += ((int)hb8[r0.x * 64 + lane] + (int)hb8[r0.y * 64 + lane])
               + ((int)hb8[r0.z * 64 + lane] + (int)hb8[r0.w * 64 + lane]);
        j += 4;
    }
    for (; j < deg; ++j) acc_i += (int)hb8[row[j] * 64 + lane];

    const float acc = (float)acc_i * (maxc[lane] * (1.0f / 127.0f));
    float h2 = fmaxf(fmaf(di, acc, bg[lane]), 0.0f);

    float sum = h + h2;
#pragma unroll
    for (int o = 32; o > 0; o >>= 1) sum += __shfl_xor(sum, o, 64);
    const float mu = sum * (1.0f / 128.0f);

    const float d0 = h - mu;
    const float d1 = h2 - mu;
    float vs = d0 * d0 + d1 * d1;
#pragma unroll
    for (int o = 32; o > 0; o >>= 1) vs += __shfl_xor(vs, o, 64);
    const float r = rsqrtf(vs * (1.0f / 128.0f) + EPS_);

    out[n * 128 + lane]      = d0 * r * gamma[lane]      + beta[lane];
    out[n * 128 + 64 + lane] = d1 * r * gamma[64 + lane] + beta[64 + lane];
}

// ---------------------------------------------------------------------------
extern "C" void kernel_launch(void* const* d_in, const int* in_sizes, int n_in,
                              void* d_out, int out_size, void* d_ws, size_t ws_size,
                              hipStream_t stream)
{
    const float* x     = (const float*)d_in[0];
    const int*   edge  = (const int*)  d_in[1];   // [2, E]: row0 = src, row1 = dst
    const float* W1    = (const float*)d_in[2];
    const float* b1    = (const float*)d_in[3];
    const float* Wg    = (const float*)d_in[4];
    const float* bg    = (const float*)d_in[5];
    const float* gamma = (const float*)d_in[6];
    const float* beta  = (const float*)d_in[7];
    float*       out   = (float*)d_out;

    // Workspace layout (~45.6 MB): hb_g(bf16) | hb8(int8) | ell | cnt | maxc
    char*  ws  = (char*)d_ws;
    size_t p   = 0;
    unsigned short* hb_g = (unsigned short*)(ws + p); p += (size_t)N_NODES * 64 * sizeof(unsigned short);
    signed char*    hb8  = (signed char*)   (ws + p); p += (size_t)N_NODES * 64 * sizeof(signed char);
    int*            ell  = (int*)           (ws + p); p += (size_t)N_NODES * PAD * sizeof(int);
    int*            cnt  = (int*)           (ws + p); p += (size_t)N_NODES * sizeof(int);
    float*          maxc = (float*)         (ws + p);

    const int* src = edge;
    const int* dst = edge + N_EDGES;

    hipMemsetAsync(cnt,  0, (size_t)N_NODES * sizeof(int), stream);
    hipMemsetAsync(maxc, 0, 64 * sizeof(float), stream);

    build_lin_kernel<<<NB_BUILD, 256, 0, stream>>>(src, dst, x, W1, b1, Wg,
                                                   cnt, ell, hb_g);
    maxc_kernel<<<512, 256, 0, stream>>>(cnt, hb_g, (unsigned int*)maxc);
    quant_kernel<<<(N_NODES * 32 + 255) / 256, 256, 0, stream>>>(
        cnt, (const unsigned int*)hb_g, maxc, (unsigned short*)hb8);
    gather_final_kernel<<<(N_NODES + 3) / 4, 256, 0, stream>>>(
        x, W1, b1, hb8, cnt, ell, maxc, bg, gamma, beta, out);
}